// Round 14
// baseline (157.262 us; speedup 1.0000x reference)
//
#include <hip/hip_runtime.h>
#include <hip/hip_fp16.h>
#include <stdint.h>

#define TT 4
#define BB 8
#define CC 512
#define NN 1024
#define HH 8

typedef unsigned char u8;
typedef _Float16 f16x8 __attribute__((ext_vector_type(8)));
typedef float f32x16 __attribute__((ext_vector_type(16)));

#define WF_BYTES ((size_t)2*64*512*16)        /* 1 MiB per weight (fp16x2 frags) */
#define SZ_SPIKE ((size_t)TT*BB*CC*NN)        /* 16 MiB */
#define SZ_GATE  ((size_t)TT*BB*HH*NN)        /* 256 KiB */

union U4H { uint4 u; f16x8 v; };
__device__ __forceinline__ f16x8 ash(uint4 u){ U4H x; x.u = u; return x.v; }

#define MFMA_F16(a,b,c) __builtin_amdgcn_mfma_f32_32x32x16_f16((a),(b),(c),0,0,0)

__device__ __forceinline__ void gld_lds4(const void* g, void* l){
  __builtin_amdgcn_global_load_lds((const __attribute__((address_space(1))) void*)g,
                                   (__attribute__((address_space(3))) void*)l, 4, 0, 0);
}

#define WAITVM(N) asm volatile("s_waitcnt vmcnt(" #N ")" ::: "memory")
#define WAITLGKM0 asm volatile("s_waitcnt lgkmcnt(0)" ::: "memory")
#define SBAR() __builtin_amdgcn_s_barrier()
#define VMFENCE() asm volatile("" ::: "memory")   /* pin VMEM issue order (FIFO) */

// fp16x2 split of a scaled fp32: xs = h + m + r, |r| <= 2^-24 |xs|
__device__ __forceinline__ void split16(float xs, uint32_t& h, uint32_t& m){
  __half hh = __float2half(xs);
  float hf = __half2float(hh);
  __half mm = __float2half(xs - hf);
  h = __half_as_ushort(hh);
  m = __half_as_ushort(mm);
}

// ---------------------------------------------------------------------------
// prep: W [512x512] fp32 -> fp16x2 frags (scale 64), layout [s][kh64][row512]x16B
// ---------------------------------------------------------------------------
__global__ __launch_bounds__(256)
void k_prep(const float* __restrict__ W0, const float* __restrict__ W1,
            const float* __restrict__ W2,
            u8* __restrict__ D0, u8* __restrict__ D1, u8* __restrict__ D2)
{
  const int which = blockIdx.y;
  const float* W = (which == 0) ? W0 : (which == 1) ? W1 : W2;
  u8* D = (which == 0) ? D0 : (which == 1) ? D1 : D2;
  const int tg  = blockIdx.x * 256 + threadIdx.x;
  const int row = tg >> 6;
  const int kh  = tg & 63;
  uint32_t Hw[4], Mw[4];
#pragma unroll
  for (int p = 0; p < 4; ++p){
    uint32_t h0, m0, h1, m1;
    split16(W[row * CC + kh * 8 + 2*p    ] * 64.0f, h0, m0);
    split16(W[row * CC + kh * 8 + 2*p + 1] * 64.0f, h1, m1);
    Hw[p] = h0 | (h1 << 16);
    Mw[p] = m0 | (m1 << 16);
  }
  *(uint4*)(D + ((size_t)(0*64 + kh)*512 + row) * 16) = make_uint4(Hw[0],Hw[1],Hw[2],Hw[3]);
  *(uint4*)(D + ((size_t)(1*64 + kh)*512 + row) * 16) = make_uint4(Mw[0],Mw[1],Mw[2],Mw[3]);
}

// ---------------------------------------------------------------------------
// q/k path, PHASE-SPLIT: 8 waves x (64d x 128col), block = 512d x 128col.
// K64 tiles (8 iters), 4 self-paced phases/tile (8 ds_read + 24 MFMA each,
// setprio bracket), ONE barrier/tile; X burst + per-phase A quarters with
// counted vmcnt (A(T+1) stays in flight across the X-drain).
//   k-path -> u8 spikes Sk;  q-path -> head-OR gate Aa (wave wid == head wid)
// grid 512: lg = (path*8+b)*32 + n0i, XCD-chunked swizzle
// ---------------------------------------------------------------------------
__global__ __launch_bounds__(512, 2)
void k_qk(const float* __restrict__ Q, const float* __restrict__ K,
          const u8* __restrict__ WFq, const u8* __restrict__ WFk,
          const float* __restrict__ qg, const float* __restrict__ qb,
          const float* __restrict__ qm, const float* __restrict__ qv,
          const float* __restrict__ kg, const float* __restrict__ kb,
          const float* __restrict__ km, const float* __restrict__ kv,
          u8* __restrict__ Sk, u8* __restrict__ Aa)
{
  __shared__ uint4 frag[2][2048];               // ring-2: [buf][(s*8+oct)*128+col] 2x32KB

  const int hw = blockIdx.x;
  const int lg = (hw & 7) * 64 + (hw >> 3);     // 512 = 8 x 64, bijective
  const int n0i  = lg & 31;
  const int b    = (lg >> 5) & 7;
  const int path = (lg >> 8) & 1;
  const int n0 = n0i << 5;
  const float* X = path ? K : Q;
  const u8* WF = path ? WFk : WFq;

  const int tid = threadIdx.x, lane = tid & 63, wid = tid >> 6;   // wid 0..7
  const int hi = lane >> 5, ln31 = lane & 31;

  // split role: col c, k-16-group kq (k = tile*64 + kq*16 + j)
  const int c  = tid & 127;
  const int kq = tid >> 7;                      // 0..3
  const int ct_t = c >> 5, nn = c & 31;
  const float* Xb = X + ((size_t)(ct_t*BB + b)*CC)*NN + n0 + nn;

  f32x16 acc[4][2];                             // [t=ct][rt], 128 AGPR
#pragma unroll
  for (int i = 0; i < 4; ++i)
#pragma unroll
    for (int j = 0; j < 2; ++j)
#pragma unroll
      for (int r = 0; r < 16; ++r) acc[i][j][r] = 0.0f;

  uint4 A0[4], A1[4], A2[4], A3[4];             // per-phase quarters [s*2+rt]
  float xr[16];                                 // X stage (16 elems/thread)

  auto loadX = [&](int tile){
    const float* xp = Xb + (size_t)(tile*64 + kq*16)*NN;
#pragma unroll
    for (int j = 0; j < 16; ++j) xr[j] = xp[(size_t)j*NN];
  };
  auto split_write = [&](int fb){
#pragma unroll
    for (int half = 0; half < 2; ++half){
      uint32_t hw_[4], mw_[4];
#pragma unroll
      for (int p = 0; p < 4; ++p){
        uint32_t ha, ma, hb2, mb2;
        split16(xr[half*8 + 2*p    ] * 512.0f, ha, ma);
        split16(xr[half*8 + 2*p + 1] * 512.0f, hb2, mb2);
        hw_[p] = ha | (hb2 << 16);
        mw_[p] = ma | (mb2 << 16);
      }
      const int oct = kq*2 + half;              // k-octet 0..7 within K64
      frag[fb][      oct*128 + c] = make_uint4(hw_[0],hw_[1],hw_[2],hw_[3]);
      frag[fb][(8 + oct)*128 + c] = make_uint4(mw_[0],mw_[1],mw_[2],mw_[3]);
    }
  };

#define LOADA(T, PH, A_) { \
    _Pragma("unroll") \
    for (int s = 0; s < 2; ++s) \
      _Pragma("unroll") \
      for (int rt = 0; rt < 2; ++rt) \
        A_[s*2 + rt] = *(const uint4*)(WF + \
            ((size_t)(s*64 + (T)*8 + (PH)*2 + hi)*512 \
             + wid*64 + rt*32 + ln31) * 16); }

#define MPHASE(FB, KS, A_) { \
    const int oct_ = (KS)*2 + hi; \
    __builtin_amdgcn_s_setprio(1); \
    _Pragma("unroll") \
    for (int ct = 0; ct < 4; ++ct){ \
      f16x8 bh = ash(frag[FB][      oct_*128 + ct*32 + ln31]); \
      f16x8 bm = ash(frag[FB][(8 + oct_)*128 + ct*32 + ln31]); \
      _Pragma("unroll") \
      for (int rt = 0; rt < 2; ++rt){ \
        acc[ct][rt] = MFMA_F16(ash(A_[0*2 + rt]), bh, acc[ct][rt]); /* Wh*Xh */ \
        acc[ct][rt] = MFMA_F16(ash(A_[1*2 + rt]), bh, acc[ct][rt]); /* Wm*Xh */ \
        acc[ct][rt] = MFMA_F16(ash(A_[0*2 + rt]), bm, acc[ct][rt]); /* Wh*Xm */ \
      } } \
    __builtin_amdgcn_s_setprio(0); }

  // prologue: X0 drained+split; X1 + A(0,*) in flight
  loadX(0); VMFENCE();
  WAITVM(0);
  split_write(0);
  loadX(1); VMFENCE();
  LOADA(0,0,A0) LOADA(0,1,A1) LOADA(0,2,A2) LOADA(0,3,A3) VMFENCE();
  WAITLGKM0; SBAR();

  // tile T (fb = T&1): ph0 issues X(T+2-burst for T>=1), each phase runs
  // 8 ds_read + 24 MFMA (compiler inserts lgkm/vmcnt for its loads), then
  // refills its A-quarter for T+1. ph3: counted WAITVM(16) drains X(T+1),
  // keeps A(T+1,*) in flight; split -> buf^1; ONE barrier.
#define QK_T(T) { \
    if ((T) >= 1 && (T) <= 6) { loadX((T)+1); VMFENCE(); } \
    MPHASE((T)&1, 0, A0)  if ((T) < 7) { LOADA((T)+1, 0, A0) VMFENCE(); } \
    MPHASE((T)&1, 1, A1)  if ((T) < 7) { LOADA((T)+1, 1, A1) VMFENCE(); } \
    MPHASE((T)&1, 2, A2)  if ((T) < 7) { LOADA((T)+1, 2, A2) VMFENCE(); } \
    MPHASE((T)&1, 3, A3)  if ((T) < 7) { LOADA((T)+1, 3, A3) VMFENCE(); \
      WAITVM(16); split_write(((T)+1)&1); WAITLGKM0; SBAR(); } }

  QK_T(0) QK_T(1) QK_T(2) QK_T(3)
  QK_T(4) QK_T(5) QK_T(6) QK_T(7)
#undef QK_T
#undef MPHASE
#undef LOADA

  // ---------------- epilogue: BN + LIF (+gate for q-path) ------------------
  const float* gamma = path ? kg : qg;
  const float* beta  = path ? kb : qb;
  const float* mean  = path ? km : qm;
  const float* var   = path ? kv : qv;

  uint32_t orb = 0;                             // wave wid == head wid (64 d)
#pragma unroll
  for (int rt = 0; rt < 2; ++rt)
#pragma unroll
    for (int rg = 0; rg < 4; ++rg){
      const int dbase = wid*64 + rt*32 + rg*8 + hi*4;
      const float4 g4 = *(const float4*)&gamma[dbase];
      const float4 b4 = *(const float4*)&beta[dbase];
      const float4 m4 = *(const float4*)&mean[dbase];
      const float4 v4 = *(const float4*)&var[dbase];
      const float* gp = (const float*)&g4;
      const float* bp = (const float*)&b4;
      const float* mp = (const float*)&m4;
      const float* vp = (const float*)&v4;
#pragma unroll
      for (int j = 0; j < 4; ++j){
        const float inv = gp[j] * (1.0f / sqrtf(vp[j] + 1e-5f));
        const float c1 = inv * (1.0f/32768.0f);
        const float c0 = bp[j] - mp[j]*inv;
        const int r = rg*4 + j;
        float v = 0.f;
#pragma unroll
        for (int t = 0; t < 4; ++t){
          const float y = fmaf(acc[t][rt][r], c1, c0);
          v = 0.5f*(v + y);
          const bool s = (v >= 1.0f);
          if (s) v = 0.f;
          if (path == 1)
            Sk[((size_t)(t*BB + b)*CC + dbase + j)*NN + n0 + ln31] = (u8)s;
          else
            orb |= ((uint32_t)s) << t;
        }
      }
    }

  if (path == 0){
    orb |= __shfl_xor(orb, 32);                 // OR lane pair (l, l^32)
    if (hi == 0){
#pragma unroll
      for (int t = 0; t < 4; ++t)
        Aa[((size_t)(t*BB + b)*HH + wid)*NN + n0 + ln31] = (u8)((orb >> t) & 1);
    }
  }
}

// ---------------------------------------------------------------------------
// proj: x = (attn & k_s) exact in fp16; W fp16x2 -> 2 passes; +bias,BN,LIF
// 4 waves x (64d x 128col); block 256d x 128col; K=64 phases x8
// grid 512: lg = ((b*32+n0i)*2 + d0t), XCD-chunked swizzle
// ---------------------------------------------------------------------------
__global__ __launch_bounds__(256, 2)
void k_proj(const u8* __restrict__ Sk, const u8* __restrict__ Ag,
            const u8* __restrict__ WF, const float* __restrict__ bias,
            const float* __restrict__ gamma, const float* __restrict__ beta,
            const float* __restrict__ mean, const float* __restrict__ var,
            float* __restrict__ O)
{
  __shared__ u8   xu[3][8192];                  // ring-3: [t4][k64][n32] u8
  __shared__ uint4 frag[1024];                  // [kb8][col128]

  const int hw = blockIdx.x;
  const int lg = (hw & 7) * 64 + (hw >> 3);
  const int d0t = lg & 1;
  const int n0i = (lg >> 1) & 31;
  const int b   = (lg >> 6) & 7;
  const int n0 = n0i << 5, d0 = d0t << 8;

  const int tid = threadIdx.x, lane = tid & 63, wid = tid >> 6;
  const int hi = lane >> 5, ln31 = lane & 31;

  const int st_kh = tid >> 5, st_t = (tid >> 3) & 3, st_n4 = tid & 7;

  f32x16 acc[4][2];
#pragma unroll
  for (int t = 0; t < 4; ++t)
#pragma unroll
    for (int rt = 0; rt < 2; ++rt)
#pragma unroll
      for (int r = 0; r < 16; ++r) acc[t][rt][r] = 0.0f;

  uint4 Ap[16];
  uint32_t gword[8];
#pragma unroll
  for (int p = 0; p < 8; ++p)
    gword[p] = *(const uint32_t*)(Ag +
        ((size_t)(st_t*BB + b)*HH + p)*NN + n0 + st_n4*4);

  auto xustage = [&](int h, int buf){
#pragma unroll
    for (int i = 0; i < 8; ++i){
      const u8* g = Sk + ((size_t)((wid*BB + b)*CC) + (size_t)(h*64 + i*8 + (lane >> 3)))*NN
                       + n0 + (lane & 7)*4;
      gld_lds4(g, (void*)&xu[buf][(wid*64 + i*8)*32]);
    }
  };
  auto loadPA = [&](int p){
#pragma unroll
    for (int s = 0; s < 2; ++s)
#pragma unroll
      for (int ks = 0; ks < 4; ++ks)
#pragma unroll
        for (int rt = 0; rt < 2; ++rt)
          Ap[(s*4 + ks)*2 + rt] = *(const uint4*)(WF +
              ((size_t)(s*64 + p*8 + ks*2 + hi)*512
               + d0 + wid*64 + rt*32 + ln31) * 16);
  };
  auto stage2 = [&](int buf, uint32_t g32){
    uint32_t r[8];
#pragma unroll
    for (int cc = 0; cc < 8; ++cc)
      r[cc] = *(const uint32_t*)&xu[buf][(st_t*64 + st_kh*8 + cc)*32 + st_n4*4];
#pragma unroll
    for (int j = 0; j < 4; ++j){
      const uint32_t gm   = __builtin_amdgcn_perm(g32, g32, (uint32_t)j * 0x01010101u);
      const uint32_t selp = (uint32_t)j | (((uint32_t)j + 4u) << 8);
      uint32_t p01 = __builtin_amdgcn_perm(r[1], r[0], selp);
      uint32_t p23 = __builtin_amdgcn_perm(r[3], r[2], selp);
      uint32_t p45 = __builtin_amdgcn_perm(r[5], r[4], selp);
      uint32_t p67 = __builtin_amdgcn_perm(r[7], r[6], selp);
      uint32_t lo  = __builtin_amdgcn_perm(p23, p01, 0x05040100u) & gm;
      uint32_t hi_ = __builtin_amdgcn_perm(p67, p45, 0x05040100u) & gm;
      uint32_t w[4];
#pragma unroll
      for (int p = 0; p < 4; ++p){
        const uint32_t src = (p < 2) ? lo : hi_;
        const uint32_t b0 = (src >> ((p & 1) * 16)) & 0xFFu;
        const uint32_t b1 = (src >> ((p & 1) * 16 + 8)) & 0xFFu;
        w[p] = (b0 ? 0x3C00u : 0u) | (b1 ? 0x3C000000u : 0u);
      }
      frag[st_kh*128 + st_t*32 + st_n4*4 + j] = make_uint4(w[0], w[1], w[2], w[3]);
    }
  };
  auto mstepP = [&](){
#pragma unroll
    for (int ks = 0; ks < 4; ++ks){
      const int kbi = ks*2 + hi;
#pragma unroll
      for (int ct = 0; ct < 4; ++ct){
        const int fb = ct*32 + ln31;
        f16x8 bb = ash(frag[kbi*128 + fb]);
#pragma unroll
        for (int rt = 0; rt < 2; ++rt){
          acc[ct][rt] = MFMA_F16(ash(Ap[(0*4 + ks)*2 + rt]), bb, acc[ct][rt]);
          acc[ct][rt] = MFMA_F16(ash(Ap[(1*4 + ks)*2 + rt]), bb, acc[ct][rt]);
        }
      }
    }
  };

#define PJ_PH(P, VM) { \
    WAITVM(VM); SBAR(); \
    loadPA(P); VMFENCE(); \
    if ((P) < 6) { xustage((P)+2, ((P)+2)%3); VMFENCE(); } \
    stage2((P)%3, gword[P]); \
    WAITLGKM0; SBAR(); \
    mstepP(); }

  xustage(0, 0); VMFENCE(); xustage(1, 1); VMFENCE();
  PJ_PH(0,8) PJ_PH(1,8) PJ_PH(2,8) PJ_PH(3,8)
  PJ_PH(4,8) PJ_PH(5,8) PJ_PH(6,8) PJ_PH(7,0)
#undef PJ_PH

#pragma unroll
  for (int rt = 0; rt < 2; ++rt)
#pragma unroll
    for (int rg = 0; rg < 4; ++rg){
      const int dbase = d0 + wid*64 + rt*32 + rg*8 + hi*4;
      const float4 g4 = *(const float4*)&gamma[dbase];
      const float4 b4 = *(const float4*)&beta[dbase];
      const float4 m4 = *(const float4*)&mean[dbase];
      const float4 v4 = *(const float4*)&var[dbase];
      const float4 s4 = *(const float4*)&bias[dbase];
      const float* gp = (const float*)&g4;
      const float* bp = (const float*)&b4;
      const float* mp = (const float*)&m4;
      const float* vp = (const float*)&v4;
      const float* sp = (const float*)&s4;
#pragma unroll
      for (int j = 0; j < 4; ++j){
        const float inv = gp[j] * (1.0f / sqrtf(vp[j] + 1e-5f));
        const float c1 = inv * (1.0f/64.0f);
        const float c0 = (sp[j] - mp[j])*inv + bp[j];
        const int r = rg*4 + j;
        float v = 0.f;
#pragma unroll
        for (int t = 0; t < 4; ++t){
          const float y = fmaf(acc[t][rt][r], c1, c0);
          v = 0.5f*(v + y);
          const bool s = (v >= 1.0f);
          if (s) v = 0.f;
          O[((size_t)(t*BB + b)*CC + dbase + j)*NN + n0 + ln31] = s ? 1.f : 0.f;
        }
      }
    }
}

// ---------------------------------------------------------------------------
extern "C" void kernel_launch(void* const* d_in, const int* in_sizes, int n_in,
                              void* d_out, int out_size, void* d_ws, size_t ws_size,
                              hipStream_t stream)
{
  const float* q   = (const float*)d_in[0];
  const float* k   = (const float*)d_in[1];
  const float* qw  = (const float*)d_in[2];
  const float* kw  = (const float*)d_in[3];
  const float* pw  = (const float*)d_in[4];
  const float* pb  = (const float*)d_in[5];
  const float* qg  = (const float*)d_in[6];
  const float* qbt = (const float*)d_in[7];
  const float* qm  = (const float*)d_in[8];
  const float* qv  = (const float*)d_in[9];
  const float* kg  = (const float*)d_in[10];
  const float* kbt = (const float*)d_in[11];
  const float* km  = (const float*)d_in[12];
  const float* kv  = (const float*)d_in[13];
  const float* pg  = (const float*)d_in[14];
  const float* pbt = (const float*)d_in[15];
  const float* pm  = (const float*)d_in[16];
  const float* pv  = (const float*)d_in[17];

  u8* WFq = (u8*)d_ws;
  u8* WFk = WFq + WF_BYTES;
  u8* WFp = WFk + WF_BYTES;
  u8* Sk  = WFp + WF_BYTES;
  u8* Aa  = Sk + SZ_SPIKE;
  const size_t need = 3*WF_BYTES + SZ_SPIKE + SZ_GATE;
  if (ws_size < need) return;

  k_prep<<<dim3(128, 3), 256, 0, stream>>>(qw, kw, pw, WFq, WFk, WFp);
  k_qk<<<512, 512, 0, stream>>>(q, k, WFq, WFk,
                                qg, qbt, qm, qv, kg, kbt, km, kv, Sk, Aa);
  k_proj<<<512, 256, 0, stream>>>(Sk, Aa, WFp, pb, pg, pbt, pm, pv, (float*)d_out);
}

// Round 15
// 156.897 us; speedup vs baseline: 1.0023x; 1.0023x over previous
//
#include <hip/hip_runtime.h>
#include <hip/hip_fp16.h>
#include <stdint.h>

#define TT 4
#define BB 8
#define CC 512
#define NN 1024
#define HH 8

typedef unsigned char u8;
typedef _Float16 f16x8 __attribute__((ext_vector_type(8)));
typedef float f32x16 __attribute__((ext_vector_type(16)));

#define WF_BYTES ((size_t)2*64*512*16)        /* 1 MiB per weight (fp16x2 frags) */
#define SZ_SPIKE ((size_t)TT*BB*CC*NN)        /* 16 MiB */
#define SZ_GATE  ((size_t)TT*BB*HH*NN)        /* 256 KiB */

union U4H { uint4 u; f16x8 v; };
__device__ __forceinline__ f16x8 ash(uint4 u){ U4H x; x.u = u; return x.v; }

#define MFMA_F16(a,b,c) __builtin_amdgcn_mfma_f32_32x32x16_f16((a),(b),(c),0,0,0)

__device__ __forceinline__ void gld_lds4(const void* g, void* l){
  __builtin_amdgcn_global_load_lds((const __attribute__((address_space(1))) void*)g,
                                   (__attribute__((address_space(3))) void*)l, 4, 0, 0);
}

#define WAITVM(N) asm volatile("s_waitcnt vmcnt(" #N ")" ::: "memory")
#define WAITLGKM0 asm volatile("s_waitcnt lgkmcnt(0)" ::: "memory")
#define SBAR() __builtin_amdgcn_s_barrier()
#define VMFENCE() asm volatile("" ::: "memory")   /* pin VMEM issue order (FIFO) */

// fp16x2 split of a scaled fp32: xs = h + m + r, |r| <= 2^-24 |xs|
__device__ __forceinline__ void split16(float xs, uint32_t& h, uint32_t& m){
  __half hh = __float2half(xs);
  float hf = __half2float(hh);
  __half mm = __float2half(xs - hf);
  h = __half_as_ushort(hh);
  m = __half_as_ushort(mm);
}

// ---------------------------------------------------------------------------
// prep: W [512x512] fp32 -> fp16x2 frags (scale 64), layout [s][kh64][row512]x16B
// ---------------------------------------------------------------------------
__global__ __launch_bounds__(256)
void k_prep(const float* __restrict__ W0, const float* __restrict__ W1,
            const float* __restrict__ W2,
            u8* __restrict__ D0, u8* __restrict__ D1, u8* __restrict__ D2)
{
  const int which = blockIdx.y;
  const float* W = (which == 0) ? W0 : (which == 1) ? W1 : W2;
  u8* D = (which == 0) ? D0 : (which == 1) ? D1 : D2;
  const int tg  = blockIdx.x * 256 + threadIdx.x;
  const int row = tg >> 6;
  const int kh  = tg & 63;
  uint32_t Hw[4], Mw[4];
#pragma unroll
  for (int p = 0; p < 4; ++p){
    uint32_t h0, m0, h1, m1;
    split16(W[row * CC + kh * 8 + 2*p    ] * 64.0f, h0, m0);
    split16(W[row * CC + kh * 8 + 2*p + 1] * 64.0f, h1, m1);
    Hw[p] = h0 | (h1 << 16);
    Mw[p] = m0 | (m1 << 16);
  }
  *(uint4*)(D + ((size_t)(0*64 + kh)*512 + row) * 16) = make_uint4(Hw[0],Hw[1],Hw[2],Hw[3]);
  *(uint4*)(D + ((size_t)(1*64 + kh)*512 + row) * 16) = make_uint4(Mw[0],Mw[1],Mw[2],Mw[3]);
}

// ---------------------------------------------------------------------------
// q/k path, PHASE-SPLIT: 8 waves x (64d x 128col), block = 512d x 128col.
// K64 tiles (8 iters), 4 self-paced phases/tile (8 ds_read + 24 MFMA each,
// setprio bracket), ONE barrier/tile; X burst + per-phase A quarters with
// counted vmcnt (A(T+1) stays in flight across the X-drain).
//   k-path -> u8 spikes Sk;  q-path -> head-OR gate Aa (wave wid == head wid)
// grid 512: lg = (path*8+b)*32 + n0i, XCD-chunked swizzle
// ---------------------------------------------------------------------------
__global__ __launch_bounds__(512, 2)
void k_qk(const float* __restrict__ Q, const float* __restrict__ K,
          const u8* __restrict__ WFq, const u8* __restrict__ WFk,
          const float* __restrict__ qg, const float* __restrict__ qb,
          const float* __restrict__ qm, const float* __restrict__ qv,
          const float* __restrict__ kg, const float* __restrict__ kb,
          const float* __restrict__ km, const float* __restrict__ kv,
          u8* __restrict__ Sk, u8* __restrict__ Aa)
{
  __shared__ uint4 frag[2][2048];               // ring-2: [buf][(s*8+oct)*128+col] 2x32KB

  const int hw = blockIdx.x;
  const int lg = (hw & 7) * 64 + (hw >> 3);     // 512 = 8 x 64, bijective
  const int n0i  = lg & 31;
  const int b    = (lg >> 5) & 7;
  const int path = (lg >> 8) & 1;
  const int n0 = n0i << 5;
  const float* X = path ? K : Q;
  const u8* WF = path ? WFk : WFq;

  const int tid = threadIdx.x, lane = tid & 63, wid = tid >> 6;   // wid 0..7
  const int hi = lane >> 5, ln31 = lane & 31;

  // split role: col c, k-16-group kq (k = tile*64 + kq*16 + j)
  const int c  = tid & 127;
  const int kq = tid >> 7;                      // 0..3
  const int ct_t = c >> 5, nn = c & 31;
  const float* Xb = X + ((size_t)(ct_t*BB + b)*CC)*NN + n0 + nn;

  f32x16 acc[4][2];                             // [t=ct][rt], 128 AGPR
#pragma unroll
  for (int i = 0; i < 4; ++i)
#pragma unroll
    for (int j = 0; j < 2; ++j)
#pragma unroll
      for (int r = 0; r < 16; ++r) acc[i][j][r] = 0.0f;

  uint4 A0[4], A1[4], A2[4], A3[4];             // per-phase quarters [s*2+rt]
  float xr[16];                                 // X stage (16 elems/thread)

  auto loadX = [&](int tile){
    const float* xp = Xb + (size_t)(tile*64 + kq*16)*NN;
#pragma unroll
    for (int j = 0; j < 16; ++j) xr[j] = xp[(size_t)j*NN];
  };
  auto split_write = [&](int fb){
#pragma unroll
    for (int half = 0; half < 2; ++half){
      uint32_t hw_[4], mw_[4];
#pragma unroll
      for (int p = 0; p < 4; ++p){
        uint32_t ha, ma, hb2, mb2;
        split16(xr[half*8 + 2*p    ] * 512.0f, ha, ma);
        split16(xr[half*8 + 2*p + 1] * 512.0f, hb2, mb2);
        hw_[p] = ha | (hb2 << 16);
        mw_[p] = ma | (mb2 << 16);
      }
      const int oct = kq*2 + half;              // k-octet 0..7 within K64
      frag[fb][      oct*128 + c] = make_uint4(hw_[0],hw_[1],hw_[2],hw_[3]);
      frag[fb][(8 + oct)*128 + c] = make_uint4(mw_[0],mw_[1],mw_[2],mw_[3]);
    }
  };

#define LOADA(T, PH, A_) { \
    _Pragma("unroll") \
    for (int s = 0; s < 2; ++s) \
      _Pragma("unroll") \
      for (int rt = 0; rt < 2; ++rt) \
        A_[s*2 + rt] = *(const uint4*)(WF + \
            ((size_t)(s*64 + (T)*8 + (PH)*2 + hi)*512 \
             + wid*64 + rt*32 + ln31) * 16); }

#define MPHASE(FB, KS, A_) { \
    const int oct_ = (KS)*2 + hi; \
    __builtin_amdgcn_s_setprio(1); \
    _Pragma("unroll") \
    for (int ct = 0; ct < 4; ++ct){ \
      f16x8 bh = ash(frag[FB][      oct_*128 + ct*32 + ln31]); \
      f16x8 bm = ash(frag[FB][(8 + oct_)*128 + ct*32 + ln31]); \
      _Pragma("unroll") \
      for (int rt = 0; rt < 2; ++rt){ \
        acc[ct][rt] = MFMA_F16(ash(A_[0*2 + rt]), bh, acc[ct][rt]); /* Wh*Xh */ \
        acc[ct][rt] = MFMA_F16(ash(A_[1*2 + rt]), bh, acc[ct][rt]); /* Wm*Xh */ \
        acc[ct][rt] = MFMA_F16(ash(A_[0*2 + rt]), bm, acc[ct][rt]); /* Wh*Xm */ \
      } } \
    __builtin_amdgcn_s_setprio(0); }

  // prologue: X0 drained+split; X1 + A(0,*) in flight
  loadX(0); VMFENCE();
  WAITVM(0);
  split_write(0);
  loadX(1); VMFENCE();
  LOADA(0,0,A0) LOADA(0,1,A1) LOADA(0,2,A2) LOADA(0,3,A3) VMFENCE();
  WAITLGKM0; SBAR();

  // tile T (fb = T&1): ph0 issues X(T+2-burst for T>=1), each phase runs
  // 8 ds_read + 24 MFMA (compiler inserts lgkm/vmcnt for its loads), then
  // refills its A-quarter for T+1. ph3: counted WAITVM(16) drains X(T+1),
  // keeps A(T+1,*) in flight; split -> buf^1; ONE barrier.
#define QK_T(T) { \
    if ((T) >= 1 && (T) <= 6) { loadX((T)+1); VMFENCE(); } \
    MPHASE((T)&1, 0, A0)  if ((T) < 7) { LOADA((T)+1, 0, A0) VMFENCE(); } \
    MPHASE((T)&1, 1, A1)  if ((T) < 7) { LOADA((T)+1, 1, A1) VMFENCE(); } \
    MPHASE((T)&1, 2, A2)  if ((T) < 7) { LOADA((T)+1, 2, A2) VMFENCE(); } \
    MPHASE((T)&1, 3, A3)  if ((T) < 7) { LOADA((T)+1, 3, A3) VMFENCE(); \
      WAITVM(16); split_write(((T)+1)&1); WAITLGKM0; SBAR(); } }

  QK_T(0) QK_T(1) QK_T(2) QK_T(3)
  QK_T(4) QK_T(5) QK_T(6) QK_T(7)
#undef QK_T
#undef MPHASE
#undef LOADA

  // ---------------- epilogue: BN + LIF (+gate for q-path) ------------------
  const float* gamma = path ? kg : qg;
  const float* beta  = path ? kb : qb;
  const float* mean  = path ? km : qm;
  const float* var   = path ? kv : qv;

  uint32_t orb = 0;                             // wave wid == head wid (64 d)
#pragma unroll
  for (int rt = 0; rt < 2; ++rt)
#pragma unroll
    for (int rg = 0; rg < 4; ++rg){
      const int dbase = wid*64 + rt*32 + rg*8 + hi*4;
      const float4 g4 = *(const float4*)&gamma[dbase];
      const float4 b4 = *(const float4*)&beta[dbase];
      const float4 m4 = *(const float4*)&mean[dbase];
      const float4 v4 = *(const float4*)&var[dbase];
      const float* gp = (const float*)&g4;
      const float* bp = (const float*)&b4;
      const float* mp = (const float*)&m4;
      const float* vp = (const float*)&v4;
#pragma unroll
      for (int j = 0; j < 4; ++j){
        const float inv = gp[j] * (1.0f / sqrtf(vp[j] + 1e-5f));
        const float c1 = inv * (1.0f/32768.0f);
        const float c0 = bp[j] - mp[j]*inv;
        const int r = rg*4 + j;
        float v = 0.f;
#pragma unroll
        for (int t = 0; t < 4; ++t){
          const float y = fmaf(acc[t][rt][r], c1, c0);
          v = 0.5f*(v + y);
          const bool s = (v >= 1.0f);
          if (s) v = 0.f;
          if (path == 1)
            Sk[((size_t)(t*BB + b)*CC + dbase + j)*NN + n0 + ln31] = (u8)s;
          else
            orb |= ((uint32_t)s) << t;
        }
      }
    }

  if (path == 0){
    orb |= __shfl_xor(orb, 32);                 // OR lane pair (l, l^32)
    if (hi == 0){
#pragma unroll
      for (int t = 0; t < 4; ++t)
        Aa[((size_t)(t*BB + b)*HH + wid)*NN + n0 + ln31] = (u8)((orb >> t) & 1);
    }
  }
}

// ---------------------------------------------------------------------------
// proj: x = (attn & k_s) exact in fp16; W fp16x2 -> 2 passes; +bias,BN,LIF
// 4 waves x (64d x 128col); block 256d x 128col; K=64 phases x8
// grid 512: lg = ((b*32+n0i)*2 + d0t), XCD-chunked swizzle
// ---------------------------------------------------------------------------
__global__ __launch_bounds__(256, 2)
void k_proj(const u8* __restrict__ Sk, const u8* __restrict__ Ag,
            const u8* __restrict__ WF, const float* __restrict__ bias,
            const float* __restrict__ gamma, const float* __restrict__ beta,
            const float* __restrict__ mean, const float* __restrict__ var,
            float* __restrict__ O)
{
  __shared__ u8   xu[3][8192];                  // ring-3: [t4][k64][n32] u8
  __shared__ uint4 frag[1024];                  // [kb8][col128]

  const int hw = blockIdx.x;
  const int lg = (hw & 7) * 64 + (hw >> 3);
  const int d0t = lg & 1;
  const int n0i = (lg >> 1) & 31;
  const int b   = (lg >> 6) & 7;
  const int n0 = n0i << 5, d0 = d0t << 8;

  const int tid = threadIdx.x, lane = tid & 63, wid = tid >> 6;
  const int hi = lane >> 5, ln31 = lane & 31;

  const int st_kh = tid >> 5, st_t = (tid >> 3) & 3, st_n4 = tid & 7;

  f32x16 acc[4][2];
#pragma unroll
  for (int t = 0; t < 4; ++t)
#pragma unroll
    for (int rt = 0; rt < 2; ++rt)
#pragma unroll
      for (int r = 0; r < 16; ++r) acc[t][rt][r] = 0.0f;

  uint4 Ap[16];
  uint32_t gword[8];
#pragma unroll
  for (int p = 0; p < 8; ++p)
    gword[p] = *(const uint32_t*)(Ag +
        ((size_t)(st_t*BB + b)*HH + p)*NN + n0 + st_n4*4);

  auto xustage = [&](int h, int buf){
#pragma unroll
    for (int i = 0; i < 8; ++i){
      const u8* g = Sk + ((size_t)((wid*BB + b)*CC) + (size_t)(h*64 + i*8 + (lane >> 3)))*NN
                       + n0 + (lane & 7)*4;
      gld_lds4(g, (void*)&xu[buf][(wid*64 + i*8)*32]);
    }
  };
  auto loadPA = [&](int p){
#pragma unroll
    for (int s = 0; s < 2; ++s)
#pragma unroll
      for (int ks = 0; ks < 4; ++ks)
#pragma unroll
        for (int rt = 0; rt < 2; ++rt)
          Ap[(s*4 + ks)*2 + rt] = *(const uint4*)(WF +
              ((size_t)(s*64 + p*8 + ks*2 + hi)*512
               + d0 + wid*64 + rt*32 + ln31) * 16);
  };
  auto stage2 = [&](int buf, uint32_t g32){
    uint32_t r[8];
#pragma unroll
    for (int cc = 0; cc < 8; ++cc)
      r[cc] = *(const uint32_t*)&xu[buf][(st_t*64 + st_kh*8 + cc)*32 + st_n4*4];
#pragma unroll
    for (int j = 0; j < 4; ++j){
      const uint32_t gm   = __builtin_amdgcn_perm(g32, g32, (uint32_t)j * 0x01010101u);
      const uint32_t selp = (uint32_t)j | (((uint32_t)j + 4u) << 8);
      uint32_t p01 = __builtin_amdgcn_perm(r[1], r[0], selp);
      uint32_t p23 = __builtin_amdgcn_perm(r[3], r[2], selp);
      uint32_t p45 = __builtin_amdgcn_perm(r[5], r[4], selp);
      uint32_t p67 = __builtin_amdgcn_perm(r[7], r[6], selp);
      uint32_t lo  = __builtin_amdgcn_perm(p23, p01, 0x05040100u) & gm;
      uint32_t hi_ = __builtin_amdgcn_perm(p67, p45, 0x05040100u) & gm;
      uint32_t w[4];
#pragma unroll
      for (int p = 0; p < 4; ++p){
        const uint32_t src = (p < 2) ? lo : hi_;
        const uint32_t b0 = (src >> ((p & 1) * 16)) & 0xFFu;
        const uint32_t b1 = (src >> ((p & 1) * 16 + 8)) & 0xFFu;
        w[p] = (b0 ? 0x3C00u : 0u) | (b1 ? 0x3C000000u : 0u);
      }
      frag[st_kh*128 + st_t*32 + st_n4*4 + j] = make_uint4(w[0], w[1], w[2], w[3]);
    }
  };
  auto mstepP = [&](){
#pragma unroll
    for (int ks = 0; ks < 4; ++ks){
      const int kbi = ks*2 + hi;
#pragma unroll
      for (int ct = 0; ct < 4; ++ct){
        const int fb = ct*32 + ln31;
        f16x8 bb = ash(frag[kbi*128 + fb]);
#pragma unroll
        for (int rt = 0; rt < 2; ++rt){
          acc[ct][rt] = MFMA_F16(ash(Ap[(0*4 + ks)*2 + rt]), bb, acc[ct][rt]);
          acc[ct][rt] = MFMA_F16(ash(Ap[(1*4 + ks)*2 + rt]), bb, acc[ct][rt]);
        }
      }
    }
  };

#define PJ_PH(P, VM) { \
    WAITVM(VM); SBAR(); \
    loadPA(P); VMFENCE(); \
    if ((P) < 6) { xustage((P)+2, ((P)+2)%3); VMFENCE(); } \
    stage2((P)%3, gword[P]); \
    WAITLGKM0; SBAR(); \
    mstepP(); }

  xustage(0, 0); VMFENCE(); xustage(1, 1); VMFENCE();
  PJ_PH(0,8) PJ_PH(1,8) PJ_PH(2,8) PJ_PH(3,8)
  PJ_PH(4,8) PJ_PH(5,8) PJ_PH(6,8) PJ_PH(7,0)
#undef PJ_PH

#pragma unroll
  for (int rt = 0; rt < 2; ++rt)
#pragma unroll
    for (int rg = 0; rg < 4; ++rg){
      const int dbase = d0 + wid*64 + rt*32 + rg*8 + hi*4;
      const float4 g4 = *(const float4*)&gamma[dbase];
      const float4 b4 = *(const float4*)&beta[dbase];
      const float4 m4 = *(const float4*)&mean[dbase];
      const float4 v4 = *(const float4*)&var[dbase];
      const float4 s4 = *(const float4*)&bias[dbase];
      const float* gp = (const float*)&g4;
      const float* bp = (const float*)&b4;
      const float* mp = (const float*)&m4;
      const float* vp = (const float*)&v4;
      const float* sp = (const float*)&s4;
#pragma unroll
      for (int j = 0; j < 4; ++j){
        const float inv = gp[j] * (1.0f / sqrtf(vp[j] + 1e-5f));
        const float c1 = inv * (1.0f/64.0f);
        const float c0 = (sp[j] - mp[j])*inv + bp[j];
        const int r = rg*4 + j;
        float v = 0.f;
#pragma unroll
        for (int t = 0; t < 4; ++t){
          const float y = fmaf(acc[t][rt][r], c1, c0);
          v = 0.5f*(v + y);
          const bool s = (v >= 1.0f);
          if (s) v = 0.f;
          O[((size_t)(t*BB + b)*CC + dbase + j)*NN + n0 + ln31] = s ? 1.f : 0.f;
        }
      }
    }
}

// ---------------------------------------------------------------------------
extern "C" void kernel_launch(void* const* d_in, const int* in_sizes, int n_in,
                              void* d_out, int out_size, void* d_ws, size_t ws_size,
                              hipStream_t stream)
{
  const float* q   = (const float*)d_in[0];
  const float* k   = (const float*)d_in[1];
  const float* qw  = (const float*)d_in[2];
  const float* kw  = (const float*)d_in[3];
  const float* pw  = (const float*)d_in[4];
  const float* pb  = (const float*)d_in[5];
  const float* qg  = (const float*)d_in[6];
  const float* qbt = (const float*)d_in[7];
  const float* qm  = (const float*)d_in[8];
  const float* qv  = (const float*)d_in[9];
  const float* kg  = (const float*)d_in[10];
  const float* kbt = (const float*)d_in[11];
  const float* km  = (const float*)d_in[12];
  const float* kv  = (const float*)d_in[13];
  const float* pg  = (const float*)d_in[14];
  const float* pbt = (const float*)d_in[15];
  const float* pm  = (const float*)d_in[16];
  const float* pv  = (const float*)d_in[17];

  u8* WFq = (u8*)d_ws;
  u8* WFk = WFq + WF_BYTES;
  u8* WFp = WFk + WF_BYTES;
  u8* Sk  = WFp + WF_BYTES;
  u8* Aa  = Sk + SZ_SPIKE;
  const size_t need = 3*WF_BYTES + SZ_SPIKE + SZ_GATE;
  if (ws_size < need) return;

  k_prep<<<dim3(128, 3), 256, 0, stream>>>(qw, kw, pw, WFq, WFk, WFp);
  k_qk<<<512, 512, 0, stream>>>(q, k, WFq, WFk,
                                qg, qbt, qm, qv, kg, kbt, km, kv, Sk, Aa);
  k_proj<<<512, 256, 0, stream>>>(Sk, Aa, WFp, pb, pg, pbt, pm, pv, (float*)d_out);
}